// Round 7
// baseline (1872.640 us; speedup 1.0000x reference)
//
#include <hip/hip_runtime.h>
#include <math.h>

#define HID 128

typedef __attribute__((ext_vector_type(8))) short short8;
typedef __attribute__((ext_vector_type(4))) float f32x4;

__device__ __forceinline__ float bf2f(unsigned int u16) {
  union { unsigned int i; float f; } x; x.i = u16 << 16; return x.f;
}
__device__ __forceinline__ unsigned short f2bf(float f) {
  union { float f; unsigned int i; } x; x.f = f;
  unsigned int i = x.i;
  unsigned int r = i + 0x7FFFu + ((i >> 16) & 1u);
  return (unsigned short)(r >> 16);
}

// k-major panel layout for MFMA A/B sides:
//   panel p = row>>7, chunk J = k>>3, elem addr = p*16384 + (J*128 + (row&127))*8 + (k&7)
// Staging a BK=32 tile is a LINEAR 8 KB copy (global_load_lds legal) and
// fragment ds_read_b128 is conflict-free.

// ---------------- weight convert: k-major panels + biascat ----------------
__global__ __launch_bounds__(128) void wcvt_kernel(
    const float* __restrict__ Wq, const float* __restrict__ bq,
    const float* __restrict__ Wk, const float* __restrict__ bk,
    const float* __restrict__ Wv, const float* __restrict__ bv,
    const float* __restrict__ Ws, const float* __restrict__ bs,
    unsigned short* __restrict__ BT, float* __restrict__ biascat)
{
  int id = blockIdx.x;
  int l = id / 1664;
  int n = id - l * 1664;
  int k = threadIdx.x;
  const float* W; const float* bias; int nl, ldb;
  if (n < 512)       { W = Wq + (size_t)l * 65536; bias = bq + (size_t)l * 512; nl = n;        ldb = 512; }
  else if (n < 1024) { W = Wk + (size_t)l * 65536; bias = bk + (size_t)l * 512; nl = n - 512;  ldb = 512; }
  else if (n < 1536) { W = Wv + (size_t)l * 65536; bias = bv + (size_t)l * 512; nl = n - 1024; ldb = 512; }
  else               { W = Ws + (size_t)l * 16384; bias = bs + (size_t)l * 128; nl = n - 1536; ldb = 128; }
  size_t dst = (size_t)l * 212992 + (size_t)(n >> 7) * 16384
             + (size_t)((k >> 3) * 128 + (n & 127)) * 8 + (k & 7);
  BT[dst] = f2bf(W[(size_t)k * ldb + nl]);
  if (k == 0) biascat[(size_t)l * 1664 + n] = bias[nl];
}

// ---------------- lin0: hb panels = bf16(x @ W + b) ----------
__global__ __launch_bounds__(128) void lin0_kernel(
    const float* __restrict__ x, const float* __restrict__ W,
    const float* __restrict__ b, unsigned short* __restrict__ hb, int N, int inF)
{
  __shared__ float xs[128];
  int n = blockIdx.x;
  int t = threadIdx.x;
  if (t < inF) xs[t] = x[(size_t)n * inF + t];
  __syncthreads();
  float acc = b[t];
  for (int k = 0; k < inF; k++) acc += xs[k] * W[(size_t)k * 128 + t];
  hb[(size_t)(n >> 7) * 16384 + (size_t)((t >> 3) * 128 + (n & 127)) * 8 + (t & 7)] = f2bf(acc);
}

// ---------------- MFMA projection GEMM ----------------
// grid (nPanels, 13); 4 waves; wave 64x64 via 4x4 16x16 tiles; operand-swapped
// MFMA -> lane f32x4 = 4 consecutive cols of one row -> 8-B packed stores.
// cols: [0,512)->q[row][c]; [512,1024)->kv[row][c]; [1024,1536)->kv[row][512+c];
// [1536,1664)->skipb[row][c] (bf16).
__global__ __launch_bounds__(256) void proj_mfma_kernel(
    const unsigned short* __restrict__ A, const unsigned short* __restrict__ BT,
    const float* __restrict__ bias, int M,
    unsigned short* __restrict__ qo, unsigned short* __restrict__ kv,
    unsigned short* __restrict__ skipb)
{
  __shared__ unsigned short lsA[4096];
  __shared__ unsigned short lsB[4096];
  const int t = threadIdx.x;
  const int wv = t >> 6, ln = t & 63;
  const int wx = wv & 1, wy = wv >> 1;
  const int m0 = blockIdx.x * 128;
  const int nc = blockIdx.y;
  const int fr = ln & 15, quad = ln >> 4;

  const unsigned short* Ap = A + (size_t)blockIdx.x * 16384;
  const unsigned short* Bp = BT + (size_t)nc * 16384;

  f32x4 acc[4][4];
#pragma unroll
  for (int i = 0; i < 4; i++)
#pragma unroll
    for (int j = 0; j < 4; j++) acc[i][j] = (f32x4){0.f, 0.f, 0.f, 0.f};

  for (int kb = 0; kb < 4; kb++) {
    __syncthreads();
#pragma unroll
    for (int it = 0; it < 2; it++) {
      const int c = it * 256 + t;
      __builtin_amdgcn_global_load_lds(
          (const __attribute__((address_space(1))) void*)(Ap + (size_t)kb * 4096 + c * 8),
          (__attribute__((address_space(3))) void*)((char*)lsA + c * 16), 16, 0, 0);
      __builtin_amdgcn_global_load_lds(
          (const __attribute__((address_space(1))) void*)(Bp + (size_t)kb * 4096 + c * 8),
          (__attribute__((address_space(3))) void*)((char*)lsB + c * 16), 16, 0, 0);
    }
    __syncthreads();

    short8 af[4], bf[4];
#pragma unroll
    for (int i = 0; i < 4; i++)
      af[i] = *(const short8*)(&lsA[(size_t)(quad * 128 + wy * 64 + i * 16 + fr) * 8]);
#pragma unroll
    for (int j = 0; j < 4; j++)
      bf[j] = *(const short8*)(&lsB[(size_t)(quad * 128 + wx * 64 + j * 16 + fr) * 8]);
#pragma unroll
    for (int i = 0; i < 4; i++)
#pragma unroll
      for (int j = 0; j < 4; j++)
        acc[i][j] = __builtin_amdgcn_mfma_f32_16x16x32_bf16(bf[j], af[i], acc[i][j], 0, 0, 0);
  }

  const int region = nc >> 2;                 // 0=q 1=k 2=v 3=skip
#pragma unroll
  for (int j = 0; j < 4; j++) {
    const int colb = nc * 128 + wx * 64 + j * 16 + quad * 4;
    const float4 b4 = *(const float4*)(&bias[colb]);
    const int col = colb - region * 512;
#pragma unroll
    for (int i = 0; i < 4; i++) {
      const int row = m0 + wy * 64 + i * 16 + fr;
      if (row < M) {
        f32x4 c = acc[i][j];
        uint2 pk;
        pk.x = (unsigned int)f2bf(c[0] + b4.x) | ((unsigned int)f2bf(c[1] + b4.y) << 16);
        pk.y = (unsigned int)f2bf(c[2] + b4.z) | ((unsigned int)f2bf(c[3] + b4.w) << 16);
        if (region == 0)      *(uint2*)(qo    + (size_t)row * 512  + col)       = pk;
        else if (region == 1) *(uint2*)(kv    + (size_t)row * 1024 + col)       = pk;
        else if (region == 2) *(uint2*)(kv    + (size_t)row * 1024 + 512 + col) = pk;
        else                  *(uint2*)(skipb + (size_t)row * 128  + col)       = pk;
      }
    }
  }
}

// ---------------- CSR build ----------------
__global__ __launch_bounds__(256) void hist_kernel(
    const int* __restrict__ dst, int* __restrict__ deg, int E)
{
  int e = blockIdx.x * 256 + threadIdx.x;
  if (e < E) atomicAdd(&deg[dst[e]], 1);
}

__global__ __launch_bounds__(256) void scan_block_kernel(
    const int* __restrict__ in, int* __restrict__ out, int* __restrict__ bsums, int N)
{
  __shared__ int sm[256];
  int i = blockIdx.x * 256 + threadIdx.x;
  int v = (i < N) ? in[i] : 0;
  sm[threadIdx.x] = v; __syncthreads();
  for (int off = 1; off < 256; off <<= 1) {
    int t = (threadIdx.x >= off) ? sm[threadIdx.x - off] : 0;
    __syncthreads();
    sm[threadIdx.x] += t;
    __syncthreads();
  }
  if (i < N) out[i] = sm[threadIdx.x] - v;   // exclusive
  if (threadIdx.x == 255 && bsums) bsums[blockIdx.x] = sm[255];
}

__global__ __launch_bounds__(256) void scan_finish_kernel(
    int* __restrict__ row_start, int* __restrict__ cursor,
    const int* __restrict__ bsums_scan, int N, int E)
{
  int i = blockIdx.x * 256 + threadIdx.x;
  if (i < N) {
    int val = row_start[i] + bsums_scan[blockIdx.x];
    row_start[i] = val;
    cursor[i] = val;
  }
  if (i == 0) row_start[N] = E;
}

__global__ __launch_bounds__(256) void scatter_kernel(
    const int* __restrict__ src, const int* __restrict__ dst,
    int* __restrict__ cursor, int* __restrict__ csr_src, int E)
{
  int e = blockIdx.x * 256 + threadIdx.x;
  if (e < E) {
    int pos = atomicAdd(&cursor[dst[e]], 1);
    csr_src[pos] = src[e];
  }
}

// ---------------- fused per-node attention (one wave per dst node) ----------
// hb[d] = relu(skipb[d] + mean_h(softmax_e * v[src_e,h,:]))  (bf16 panel out)
// kv rows interleaved: [node][0..511]=k, [512..1023]=v. Depth-2 pipeline.
__global__ __launch_bounds__(256) void node_attn_kernel(
    const unsigned short* __restrict__ q, const unsigned short* __restrict__ kv,
    const unsigned short* __restrict__ skipb,
    const int* __restrict__ row_start, const int* __restrict__ csr_src,
    unsigned short* __restrict__ hb, int N)
{
  int d = (blockIdx.x * 256 + threadIdx.x) >> 6;
  int lane = threadIdx.x & 63;
  if (d >= N) return;
  int beg = row_start[d], end = row_start[d + 1];

  const uint4 qv = *(const uint4*)(q + (size_t)d * 512 + lane * 8);
  float q0 = bf2f(qv.x & 0xFFFFu), q1 = bf2f(qv.x >> 16);
  float q2 = bf2f(qv.y & 0xFFFFu), q3 = bf2f(qv.y >> 16);
  float q4 = bf2f(qv.z & 0xFFFFu), q5 = bf2f(qv.z >> 16);
  float q6 = bf2f(qv.w & 0xFFFFu), q7 = bf2f(qv.w >> 16);

  float num[8] = {0.f,0.f,0.f,0.f,0.f,0.f,0.f,0.f};
  float den = 0.f;

  auto krow = [&](int s) { return *(const uint4*)(kv + (size_t)s * 1024 + lane * 8); };
  auto vrow = [&](int s) { return *(const uint4*)(kv + (size_t)s * 1024 + 512 + lane * 8); };
  auto accum = [&](const uint4& kk, const uint4& vv) {
    float p = q0 * bf2f(kk.x & 0xFFFFu) + q1 * bf2f(kk.x >> 16)
            + q2 * bf2f(kk.y & 0xFFFFu) + q3 * bf2f(kk.y >> 16)
            + q4 * bf2f(kk.z & 0xFFFFu) + q5 * bf2f(kk.z >> 16)
            + q6 * bf2f(kk.w & 0xFFFFu) + q7 * bf2f(kk.w >> 16);
    p += __shfl_xor(p, 1);
    p += __shfl_xor(p, 2);
    p += __shfl_xor(p, 4);
    p += __shfl_xor(p, 8);
    float e = __expf(p * 0.08838834764831845f);  // 1/sqrt(128)
    den += e;
    num[0] += e * bf2f(vv.x & 0xFFFFu); num[1] += e * bf2f(vv.x >> 16);
    num[2] += e * bf2f(vv.y & 0xFFFFu); num[3] += e * bf2f(vv.y >> 16);
    num[4] += e * bf2f(vv.z & 0xFFFFu); num[5] += e * bf2f(vv.z >> 16);
    num[6] += e * bf2f(vv.w & 0xFFFFu); num[7] += e * bf2f(vv.w >> 16);
  };

  if (beg < end) {
    const int last = end - 1;
    int sA = csr_src[beg];
    int sB = csr_src[min(beg + 1, last)];
    uint4 kA = krow(sA), vA = vrow(sA);
    uint4 kB = krow(sB), vB = vrow(sB);
    for (int i = beg; i < end; i += 2) {
      int sC = csr_src[min(i + 2, last)];
      int sD = csr_src[min(i + 3, last)];
      uint4 kC = krow(sC), vC = vrow(sC);
      uint4 kD = krow(sD), vD = vrow(sD);
      accum(kA, vA);
      if (i + 1 < end) accum(kB, vB);
      kA = kC; vA = vC; kB = kD; vB = vD;
    }
  }

  float inv = (den > 0.f) ? 0.25f / den : 0.f;
#pragma unroll
  for (int j = 0; j < 8; j++) {
    float r = num[j] * inv;
    r += __shfl_xor(r, 16);   // combine 4 heads
    r += __shfl_xor(r, 32);
    num[j] = r;
  }
  if (lane < 16) {
    const uint4 sv = *(const uint4*)(skipb + (size_t)d * 128 + lane * 8);
    float o0 = fmaxf(bf2f(sv.x & 0xFFFFu) + num[0], 0.f);
    float o1 = fmaxf(bf2f(sv.x >> 16)     + num[1], 0.f);
    float o2 = fmaxf(bf2f(sv.y & 0xFFFFu) + num[2], 0.f);
    float o3 = fmaxf(bf2f(sv.y >> 16)     + num[3], 0.f);
    float o4 = fmaxf(bf2f(sv.z & 0xFFFFu) + num[4], 0.f);
    float o5 = fmaxf(bf2f(sv.z >> 16)     + num[5], 0.f);
    float o6 = fmaxf(bf2f(sv.w & 0xFFFFu) + num[6], 0.f);
    float o7 = fmaxf(bf2f(sv.w >> 16)     + num[7], 0.f);
    uint4 hv;
    hv.x = (unsigned int)f2bf(o0) | ((unsigned int)f2bf(o1) << 16);
    hv.y = (unsigned int)f2bf(o2) | ((unsigned int)f2bf(o3) << 16);
    hv.z = (unsigned int)f2bf(o4) | ((unsigned int)f2bf(o5) << 16);
    hv.w = (unsigned int)f2bf(o6) | ((unsigned int)f2bf(o7) << 16);
    *(uint4*)(hb + (size_t)(d >> 7) * 16384 + (size_t)(lane * 128 + (d & 127)) * 8) = hv;
  }
}

// ---------------- pooling from bf16 panels (batch sorted) ----------------
__global__ __launch_bounds__(128) void pool_kernel(
    const unsigned short* __restrict__ hb, const int* __restrict__ batch,
    float* __restrict__ emb, int N)
{
  int dth = threadIdx.x;
  int n0 = blockIdx.x * 128;
  int n1 = min(n0 + 128, N);
  float acc = 0.f; int cur = -1;
  for (int n = n0; n < n1; n++) {
    int g = batch[n];
    if (g != cur) {
      if (cur >= 0) atomicAdd(&emb[(size_t)cur * 128 + dth], acc);
      cur = g; acc = 0.f;
    }
    acc += bf2f(hb[(size_t)(n >> 7) * 16384
                   + (size_t)((dth >> 3) * 128 + (n & 127)) * 8 + (dth & 7)]);
  }
  if (cur >= 0) atomicAdd(&emb[(size_t)cur * 128 + dth], acc);
}

// ---------------- final score ----------------
__global__ __launch_bounds__(128) void score_kernel(
    const float* __restrict__ hemb, const float* __restrict__ temb,
    const int* __restrict__ rels,
    const float* __restrict__ wqW, const float* __restrict__ wqb,
    const float* __restrict__ wkW, const float* __restrict__ wkb,
    const float* __restrict__ rel_emb, float* __restrict__ out)
{
  const int b = blockIdx.x, i = threadIdx.x;
  __shared__ float hs[128], ts[128], hnv[128], tnv[128], red[128];
  hs[i] = hemb[(size_t)b * 128 + i];
  ts[i] = temb[(size_t)b * 128 + i];
  __syncthreads();
  float qv = wqb[i], kv = wkb[i];
  for (int k = 0; k < 128; k++) {
    qv += hs[k] * wqW[k * 128 + i];
    kv += ts[k] * wkW[k * 128 + i];
  }
  float inter = tanhf(qv * kv);
  float hx = hs[i] + inter, tx2 = ts[i] + inter;

  red[i] = hx * hx; __syncthreads();
  for (int s = 64; s > 0; s >>= 1) { if (i < s) red[i] += red[i + s]; __syncthreads(); }
  float hnorm = fmaxf(sqrtf(red[0]), 1e-12f);
  __syncthreads();
  red[i] = tx2 * tx2; __syncthreads();
  for (int s = 64; s > 0; s >>= 1) { if (i < s) red[i] += red[i + s]; __syncthreads(); }
  float tnorm = fmaxf(sqrtf(red[0]), 1e-12f);
  __syncthreads();
  hnv[i] = hx / hnorm; tnv[i] = tx2 / tnorm;
  __syncthreads();

  const float* R = rel_emb + (size_t)rels[b] * 16384 + (size_t)i * 128;
  float dot = 0.f, nrm = 0.f;
  for (int j = 0; j < 128; j++) { float r = R[j]; dot += r * tnv[j]; nrm += r * r; }
  float contrib = hnv[i] * dot / fmaxf(sqrtf(nrm), 1e-12f);
  red[i] = contrib; __syncthreads();
  for (int s = 64; s > 0; s >>= 1) { if (i < s) red[i] += red[i + s]; __syncthreads(); }
  if (i == 0) out[b] = red[0];
}

extern "C" void kernel_launch(void* const* d_in, const int* in_sizes, int n_in,
                              void* d_out, int out_size, void* d_ws, size_t ws_size,
                              hipStream_t stream)
{
  const float* h_x     = (const float*)d_in[0];
  const int*   h_ei    = (const int*)d_in[1];
  const int*   h_batch = (const int*)d_in[2];
  const float* t_x     = (const float*)d_in[3];
  const int*   t_ei    = (const int*)d_in[4];
  const int*   t_batch = (const int*)d_in[5];
  const int*   rels    = (const int*)d_in[6];
  const float* lin0_W  = (const float*)d_in[7];
  const float* lin0_b  = (const float*)d_in[8];
  const float* Wq      = (const float*)d_in[9];
  const float* bq      = (const float*)d_in[10];
  const float* Wk      = (const float*)d_in[11];
  const float* bk      = (const float*)d_in[12];
  const float* Wv      = (const float*)d_in[13];
  const float* bv      = (const float*)d_in[14];
  const float* Ws      = (const float*)d_in[15];
  const float* bs      = (const float*)d_in[16];
  const float* wqW     = (const float*)d_in[17];
  const float* wqb     = (const float*)d_in[18];
  const float* wkW     = (const float*)d_in[19];
  const float* wkb     = (const float*)d_in[20];
  const float* rel_emb = (const float*)d_in[21];

  const int N = in_sizes[2];          // 50000
  const int E = in_sizes[1] / 2;      // 400000
  const int G = in_sizes[6];          // 512
  const int inF = in_sizes[7] / 128;  // 70
  const int nPanels = (N + 127) / 128;

  char* ws = (char*)d_ws;
  size_t off = 0;
  auto alloc = [&](size_t bytes) -> void* {
    void* p = ws + off; off += (bytes + 255) & ~(size_t)255; return p;
  };
  unsigned short* hbuf  = (unsigned short*)alloc((size_t)nPanels * 16384 * 2);
  unsigned short* skipb = (unsigned short*)alloc((size_t)N * 128 * 2);
  unsigned short* qb    = (unsigned short*)alloc((size_t)N * 512 * 2);
  unsigned short* kvb   = (unsigned short*)alloc((size_t)N * 1024 * 2);
  unsigned short* BT    = (unsigned short*)alloc((size_t)3 * 212992 * 2);
  float* biascat        = (float*)alloc((size_t)3 * 1664 * 4);
  int* deg              = (int*)alloc((size_t)(N + 1) * 4);
  int* row_start        = (int*)alloc((size_t)(N + 1) * 4);
  int* cursor           = (int*)alloc((size_t)(N + 1) * 4);
  int* bsums            = (int*)alloc((size_t)1024 * 4);
  int* bsums_scan       = (int*)alloc((size_t)1024 * 4);
  int* csr_src          = (int*)alloc((size_t)E * 4);
  float* hEmb           = (float*)alloc((size_t)G * 128 * 4);
  float* tEmb           = (float*)alloc((size_t)G * 128 * 4);
  (void)ws_size; (void)n_in; (void)out_size;

  const int nScanBlocks = (N + 255) / 256;   // 196 <= 256

  // Convert weights once per call (shared by both graphs)
  wcvt_kernel<<<3 * 1664, 128, 0, stream>>>(Wq, bq, Wk, bk, Wv, bv, Ws, bs, BT, biascat);

  for (int g = 0; g < 2; g++) {
    const float* x     = g ? t_x : h_x;
    const int*   ei    = g ? t_ei : h_ei;
    const int*   batch = g ? t_batch : h_batch;
    float*       emb   = g ? tEmb : hEmb;
    const int* srcp = ei;
    const int* dstp = ei + E;

    // --- build CSR (edges grouped by dst) ---
    hipMemsetAsync(deg, 0, (size_t)(N + 1) * 4, stream);
    hist_kernel<<<(E + 255) / 256, 256, 0, stream>>>(dstp, deg, E);
    scan_block_kernel<<<nScanBlocks, 256, 0, stream>>>(deg, row_start, bsums, N);
    scan_block_kernel<<<1, 256, 0, stream>>>(bsums, bsums_scan, nullptr, nScanBlocks);
    scan_finish_kernel<<<nScanBlocks, 256, 0, stream>>>(row_start, cursor, bsums_scan, N, E);
    scatter_kernel<<<(E + 255) / 256, 256, 0, stream>>>(srcp, dstp, cursor, csr_src, E);

    lin0_kernel<<<N, 128, 0, stream>>>(x, lin0_W, lin0_b, hbuf, N, inF);
    for (int l = 0; l < 3; l++) {
      dim3 pg(nPanels, 13);
      proj_mfma_kernel<<<pg, 256, 0, stream>>>(hbuf,
          BT + (size_t)l * 212992, biascat + (size_t)l * 1664, N,
          qb, kvb, skipb);
      node_attn_kernel<<<(N + 3) / 4, 256, 0, stream>>>(qb, kvb, skipb,
          row_start, csr_src, hbuf, N);
    }
    hipMemsetAsync(emb, 0, (size_t)G * 128 * 4, stream);
    pool_kernel<<<(N + 127) / 128, 128, 0, stream>>>(hbuf, batch, emb, N);
  }

  score_kernel<<<G, 128, 0, stream>>>(hEmb, tEmb, rels, wqW, wqb, wkW, wkb,
                                      rel_emb, (float*)d_out);
}

// Round 8
// 1772.417 us; speedup vs baseline: 1.0565x; 1.0565x over previous
//
#include <hip/hip_runtime.h>
#include <math.h>

#define HID 128

typedef __attribute__((ext_vector_type(8))) short short8;
typedef __attribute__((ext_vector_type(4))) float f32x4;

__device__ __forceinline__ float bf2f(unsigned int u16) {
  union { unsigned int i; float f; } x; x.i = u16 << 16; return x.f;
}
__device__ __forceinline__ unsigned short f2bf(float f) {
  union { float f; unsigned int i; } x; x.f = f;
  unsigned int i = x.i;
  unsigned int r = i + 0x7FFFu + ((i >> 16) & 1u);
  return (unsigned short)(r >> 16);
}

// k-major panel layout for MFMA A/B sides:
//   panel p = row>>7, chunk J = k>>3, elem addr = p*16384 + (J*128 + (row&127))*8 + (k&7)
// Staging a BK=32 tile is a LINEAR 8 KB copy (global_load_lds legal) and
// fragment ds_read_b128 is conflict-free.

// ---------------- weight convert: k-major panels + biascat ----------------
__global__ __launch_bounds__(128) void wcvt_kernel(
    const float* __restrict__ Wq, const float* __restrict__ bq,
    const float* __restrict__ Wk, const float* __restrict__ bk,
    const float* __restrict__ Wv, const float* __restrict__ bv,
    const float* __restrict__ Ws, const float* __restrict__ bs,
    unsigned short* __restrict__ BT, float* __restrict__ biascat)
{
  int id = blockIdx.x;
  int l = id / 1664;
  int n = id - l * 1664;
  int k = threadIdx.x;
  const float* W; const float* bias; int nl, ldb;
  if (n < 512)       { W = Wq + (size_t)l * 65536; bias = bq + (size_t)l * 512; nl = n;        ldb = 512; }
  else if (n < 1024) { W = Wk + (size_t)l * 65536; bias = bk + (size_t)l * 512; nl = n - 512;  ldb = 512; }
  else if (n < 1536) { W = Wv + (size_t)l * 65536; bias = bv + (size_t)l * 512; nl = n - 1024; ldb = 512; }
  else               { W = Ws + (size_t)l * 16384; bias = bs + (size_t)l * 128; nl = n - 1536; ldb = 128; }
  size_t dst = (size_t)l * 212992 + (size_t)(n >> 7) * 16384
             + (size_t)((k >> 3) * 128 + (n & 127)) * 8 + (k & 7);
  BT[dst] = f2bf(W[(size_t)k * ldb + nl]);
  if (k == 0) biascat[(size_t)l * 1664 + n] = bias[nl];
}

// ---------------- lin0 (both graphs, 8 nodes/block) ----------
// hb row for node n of graph g lives at padded row g*Npad + n.
__global__ __launch_bounds__(128) void lin0_kernel(
    const float* __restrict__ xh, const float* __restrict__ xt,
    const float* __restrict__ W, const float* __restrict__ b,
    unsigned short* __restrict__ hb, int N, int inF, int Npad)
{
  __shared__ float xs[8][72];
  const int t = threadIdx.x;
  const int nb = blockIdx.x * 8;
  if (t < inF) {
#pragma unroll
    for (int nn = 0; nn < 8; nn++) {
      int n = nb + nn;
      if (n < 2 * N) {
        const float* xp = (n < N) ? (xh + (size_t)n * inF) : (xt + (size_t)(n - N) * inF);
        xs[nn][t] = xp[t];
      }
    }
  }
  __syncthreads();
  float acc[8];
#pragma unroll
  for (int nn = 0; nn < 8; nn++) acc[nn] = b[t];
  for (int k = 0; k < inF; k++) {
    float w = W[(size_t)k * 128 + t];
#pragma unroll
    for (int nn = 0; nn < 8; nn++) acc[nn] += xs[nn][k] * w;
  }
#pragma unroll
  for (int nn = 0; nn < 8; nn++) {
    int n = nb + nn;
    if (n < 2 * N) {
      int g = (n >= N) ? 1 : 0;
      int row = g * Npad + (n - g * N);
      hb[(size_t)(row >> 7) * 16384 + (size_t)((t >> 3) * 128 + (row & 127)) * 8 + (t & 7)] = f2bf(acc[nn]);
    }
  }
}

// ---------------- MFMA projection GEMM (double-buffered staging) ----------
// grid (nPanels, 13); 4 waves; wave 64x64 via 4x4 16x16 tiles; operand-swapped
// MFMA -> lane f32x4 = 4 consecutive cols of one row -> 8-B packed stores.
// cols: [0,512)->q; [512,1024)->kv[.][0..511]; [1024,1536)->kv[.][512..1023];
// [1536,1664)->skipb (all bf16).
__global__ __launch_bounds__(256) void proj_mfma_kernel(
    const unsigned short* __restrict__ A, const unsigned short* __restrict__ BT,
    const float* __restrict__ bias, int M,
    unsigned short* __restrict__ qo, unsigned short* __restrict__ kv,
    unsigned short* __restrict__ skipb)
{
  __shared__ unsigned short lsA[2][4096];
  __shared__ unsigned short lsB[2][4096];
  const int t = threadIdx.x;
  const int wv = t >> 6, ln = t & 63;
  const int wx = wv & 1, wy = wv >> 1;
  const int m0 = blockIdx.x * 128;
  const int nc = blockIdx.y;
  const int fr = ln & 15, quad = ln >> 4;

  const unsigned short* Ap = A + (size_t)blockIdx.x * 16384;
  const unsigned short* Bp = BT + (size_t)nc * 16384;

  auto stage = [&](int kb, int buf) {
#pragma unroll
    for (int it = 0; it < 2; it++) {
      const int c = it * 256 + t;
      __builtin_amdgcn_global_load_lds(
          (const __attribute__((address_space(1))) void*)(Ap + (size_t)kb * 4096 + c * 8),
          (__attribute__((address_space(3))) void*)((char*)lsA[buf] + c * 16), 16, 0, 0);
      __builtin_amdgcn_global_load_lds(
          (const __attribute__((address_space(1))) void*)(Bp + (size_t)kb * 4096 + c * 8),
          (__attribute__((address_space(3))) void*)((char*)lsB[buf] + c * 16), 16, 0, 0);
    }
  };

  f32x4 acc[4][4];
#pragma unroll
  for (int i = 0; i < 4; i++)
#pragma unroll
    for (int j = 0; j < 4; j++) acc[i][j] = (f32x4){0.f, 0.f, 0.f, 0.f};

  stage(0, 0);
  for (int kb = 0; kb < 4; kb++) {
    __syncthreads();                      // buf[kb&1] staged; prev reads done
    if (kb < 3) stage(kb + 1, (kb + 1) & 1);   // overlaps with compute below
    const unsigned short* la = lsA[kb & 1];
    const unsigned short* lb = lsB[kb & 1];
    short8 af[4], bf[4];
#pragma unroll
    for (int i = 0; i < 4; i++)
      af[i] = *(const short8*)(&la[(size_t)(quad * 128 + wy * 64 + i * 16 + fr) * 8]);
#pragma unroll
    for (int j = 0; j < 4; j++)
      bf[j] = *(const short8*)(&lb[(size_t)(quad * 128 + wx * 64 + j * 16 + fr) * 8]);
#pragma unroll
    for (int i = 0; i < 4; i++)
#pragma unroll
      for (int j = 0; j < 4; j++)
        acc[i][j] = __builtin_amdgcn_mfma_f32_16x16x32_bf16(bf[j], af[i], acc[i][j], 0, 0, 0);
  }

  const int region = nc >> 2;                 // 0=q 1=k 2=v 3=skip
#pragma unroll
  for (int j = 0; j < 4; j++) {
    const int colb = nc * 128 + wx * 64 + j * 16 + quad * 4;
    const float4 b4 = *(const float4*)(&bias[colb]);
    const int col = colb - region * 512;
#pragma unroll
    for (int i = 0; i < 4; i++) {
      const int row = m0 + wy * 64 + i * 16 + fr;
      if (row < M) {
        f32x4 c = acc[i][j];
        uint2 pk;
        pk.x = (unsigned int)f2bf(c[0] + b4.x) | ((unsigned int)f2bf(c[1] + b4.y) << 16);
        pk.y = (unsigned int)f2bf(c[2] + b4.z) | ((unsigned int)f2bf(c[3] + b4.w) << 16);
        if (region == 0)      *(uint2*)(qo    + (size_t)row * 512  + col)       = pk;
        else if (region == 1) *(uint2*)(kv    + (size_t)row * 1024 + col)       = pk;
        else if (region == 2) *(uint2*)(kv    + (size_t)row * 1024 + 512 + col) = pk;
        else                  *(uint2*)(skipb + (size_t)row * 128  + col)       = pk;
      }
    }
  }
}

// ---------------- combined CSR build (t-graph dst offset by N) ----------------
__global__ __launch_bounds__(256) void hist_kernel(
    const int* __restrict__ dst, int* __restrict__ deg, int E, int off)
{
  int e = blockIdx.x * 256 + threadIdx.x;
  if (e < E) atomicAdd(&deg[dst[e] + off], 1);
}

__global__ __launch_bounds__(256) void scan_block_kernel(
    const int* __restrict__ in, int* __restrict__ out, int* __restrict__ bsums, int N)
{
  __shared__ int sm[256];
  int i = blockIdx.x * 256 + threadIdx.x;
  int v = (i < N) ? in[i] : 0;
  sm[threadIdx.x] = v; __syncthreads();
  for (int off = 1; off < 256; off <<= 1) {
    int t = (threadIdx.x >= off) ? sm[threadIdx.x - off] : 0;
    __syncthreads();
    sm[threadIdx.x] += t;
    __syncthreads();
  }
  if (i < N) out[i] = sm[threadIdx.x] - v;   // exclusive
  if (threadIdx.x == 255 && bsums) bsums[blockIdx.x] = sm[255];
}

// single-block multi-chunk exclusive scan (nb can exceed 256)
__global__ __launch_bounds__(256) void scan_seq_kernel(
    const int* __restrict__ in, int* __restrict__ out, int nb)
{
  __shared__ int sm[256];
  __shared__ int carry;
  if (threadIdx.x == 0) carry = 0;
  __syncthreads();
  for (int base = 0; base < nb; base += 256) {
    int i = base + threadIdx.x;
    int v = (i < nb) ? in[i] : 0;
    sm[threadIdx.x] = v; __syncthreads();
    for (int off = 1; off < 256; off <<= 1) {
      int t = (threadIdx.x >= off) ? sm[threadIdx.x - off] : 0;
      __syncthreads();
      sm[threadIdx.x] += t;
      __syncthreads();
    }
    if (i < nb) out[i] = carry + sm[threadIdx.x] - v;
    __syncthreads();
    if (threadIdx.x == 0) carry += sm[255];
    __syncthreads();
  }
}

__global__ __launch_bounds__(256) void scan_finish_kernel(
    int* __restrict__ row_start, int* __restrict__ cursor,
    const int* __restrict__ bsums_scan, int Ntot, int Etot)
{
  int i = blockIdx.x * 256 + threadIdx.x;
  if (i < Ntot) {
    int val = row_start[i] + bsums_scan[blockIdx.x];
    row_start[i] = val;
    cursor[i] = val;
  }
  if (i == 0) row_start[Ntot] = Etot;
}

// stores LOCAL src ids; dst offset selects the graph's region of row_start
__global__ __launch_bounds__(256) void scatter_kernel(
    const int* __restrict__ src, const int* __restrict__ dst,
    int* __restrict__ cursor, int* __restrict__ csr_src, int E, int doff)
{
  int e = blockIdx.x * 256 + threadIdx.x;
  if (e < E) {
    int pos = atomicAdd(&cursor[dst[e] + doff], 1);
    csr_src[pos] = src[e];
  }
}

// ---------------- fused per-node attention (one wave per dst node) ----------
// hb[d] = relu(skipb[d] + mean_h(softmax_e * v[src_e,h,:]))  (bf16 panel out)
// kv rows interleaved: [node][0..511]=k, [512..1023]=v. Depth-2 pipeline.
__global__ __launch_bounds__(256) void node_attn_kernel(
    const unsigned short* __restrict__ q, const unsigned short* __restrict__ kv,
    const unsigned short* __restrict__ skipb,
    const int* __restrict__ row_start, const int* __restrict__ csr_src,
    unsigned short* __restrict__ hb, int N)
{
  int d = (blockIdx.x * 256 + threadIdx.x) >> 6;
  int lane = threadIdx.x & 63;
  if (d >= N) return;
  int beg = row_start[d], end = row_start[d + 1];

  const uint4 qv = *(const uint4*)(q + (size_t)d * 512 + lane * 8);
  float q0 = bf2f(qv.x & 0xFFFFu), q1 = bf2f(qv.x >> 16);
  float q2 = bf2f(qv.y & 0xFFFFu), q3 = bf2f(qv.y >> 16);
  float q4 = bf2f(qv.z & 0xFFFFu), q5 = bf2f(qv.z >> 16);
  float q6 = bf2f(qv.w & 0xFFFFu), q7 = bf2f(qv.w >> 16);

  float num[8] = {0.f,0.f,0.f,0.f,0.f,0.f,0.f,0.f};
  float den = 0.f;

  auto krow = [&](int s) { return *(const uint4*)(kv + (size_t)s * 1024 + lane * 8); };
  auto vrow = [&](int s) { return *(const uint4*)(kv + (size_t)s * 1024 + 512 + lane * 8); };
  auto accum = [&](const uint4& kk, const uint4& vv) {
    float p = q0 * bf2f(kk.x & 0xFFFFu) + q1 * bf2f(kk.x >> 16)
            + q2 * bf2f(kk.y & 0xFFFFu) + q3 * bf2f(kk.y >> 16)
            + q4 * bf2f(kk.z & 0xFFFFu) + q5 * bf2f(kk.z >> 16)
            + q6 * bf2f(kk.w & 0xFFFFu) + q7 * bf2f(kk.w >> 16);
    p += __shfl_xor(p, 1);
    p += __shfl_xor(p, 2);
    p += __shfl_xor(p, 4);
    p += __shfl_xor(p, 8);
    float e = __expf(p * 0.08838834764831845f);  // 1/sqrt(128)
    den += e;
    num[0] += e * bf2f(vv.x & 0xFFFFu); num[1] += e * bf2f(vv.x >> 16);
    num[2] += e * bf2f(vv.y & 0xFFFFu); num[3] += e * bf2f(vv.y >> 16);
    num[4] += e * bf2f(vv.z & 0xFFFFu); num[5] += e * bf2f(vv.z >> 16);
    num[6] += e * bf2f(vv.w & 0xFFFFu); num[7] += e * bf2f(vv.w >> 16);
  };

  if (beg < end) {
    const int last = end - 1;
    int sA = csr_src[beg];
    int sB = csr_src[min(beg + 1, last)];
    uint4 kA = krow(sA), vA = vrow(sA);
    uint4 kB = krow(sB), vB = vrow(sB);
    for (int i = beg; i < end; i += 2) {
      int sC = csr_src[min(i + 2, last)];
      int sD = csr_src[min(i + 3, last)];
      uint4 kC = krow(sC), vC = vrow(sC);
      uint4 kD = krow(sD), vD = vrow(sD);
      accum(kA, vA);
      if (i + 1 < end) accum(kB, vB);
      kA = kC; vA = vC; kB = kD; vB = vD;
    }
  }

  float inv = (den > 0.f) ? 0.25f / den : 0.f;
#pragma unroll
  for (int j = 0; j < 8; j++) {
    float r = num[j] * inv;
    r += __shfl_xor(r, 16);   // combine 4 heads
    r += __shfl_xor(r, 32);
    num[j] = r;
  }
  if (lane < 16) {
    const uint4 sv = *(const uint4*)(skipb + (size_t)d * 128 + lane * 8);
    float o0 = fmaxf(bf2f(sv.x & 0xFFFFu) + num[0], 0.f);
    float o1 = fmaxf(bf2f(sv.x >> 16)     + num[1], 0.f);
    float o2 = fmaxf(bf2f(sv.y & 0xFFFFu) + num[2], 0.f);
    float o3 = fmaxf(bf2f(sv.y >> 16)     + num[3], 0.f);
    float o4 = fmaxf(bf2f(sv.z & 0xFFFFu) + num[4], 0.f);
    float o5 = fmaxf(bf2f(sv.z >> 16)     + num[5], 0.f);
    float o6 = fmaxf(bf2f(sv.w & 0xFFFFu) + num[6], 0.f);
    float o7 = fmaxf(bf2f(sv.w >> 16)     + num[7], 0.f);
    uint4 hv;
    hv.x = (unsigned int)f2bf(o0) | ((unsigned int)f2bf(o1) << 16);
    hv.y = (unsigned int)f2bf(o2) | ((unsigned int)f2bf(o3) << 16);
    hv.z = (unsigned int)f2bf(o4) | ((unsigned int)f2bf(o5) << 16);
    hv.w = (unsigned int)f2bf(o6) | ((unsigned int)f2bf(o7) << 16);
    *(uint4*)(hb + (size_t)(d >> 7) * 16384 + (size_t)(lane * 128 + (d & 127)) * 8) = hv;
  }
}

// ---------------- pooling from bf16 panels (batch sorted) ----------------
__global__ __launch_bounds__(128) void pool_kernel(
    const unsigned short* __restrict__ hb, const int* __restrict__ batch,
    float* __restrict__ emb, int N)
{
  int dth = threadIdx.x;
  int n0 = blockIdx.x * 128;
  int n1 = min(n0 + 128, N);
  float acc = 0.f; int cur = -1;
  for (int n = n0; n < n1; n++) {
    int g = batch[n];
    if (g != cur) {
      if (cur >= 0) atomicAdd(&emb[(size_t)cur * 128 + dth], acc);
      cur = g; acc = 0.f;
    }
    acc += bf2f(hb[(size_t)(n >> 7) * 16384
                   + (size_t)((dth >> 3) * 128 + (n & 127)) * 8 + (dth & 7)]);
  }
  if (cur >= 0) atomicAdd(&emb[(size_t)cur * 128 + dth], acc);
}

// ---------------- final score ----------------
__global__ __launch_bounds__(128) void score_kernel(
    const float* __restrict__ hemb, const float* __restrict__ temb,
    const int* __restrict__ rels,
    const float* __restrict__ wqW, const float* __restrict__ wqb,
    const float* __restrict__ wkW, const float* __restrict__ wkb,
    const float* __restrict__ rel_emb, float* __restrict__ out)
{
  const int b = blockIdx.x, i = threadIdx.x;
  __shared__ float hs[128], ts[128], hnv[128], tnv[128], red[128];
  hs[i] = hemb[(size_t)b * 128 + i];
  ts[i] = temb[(size_t)b * 128 + i];
  __syncthreads();
  float qv = wqb[i], kv = wkb[i];
  for (int k = 0; k < 128; k++) {
    qv += hs[k] * wqW[k * 128 + i];
    kv += ts[k] * wkW[k * 128 + i];
  }
  float inter = tanhf(qv * kv);
  float hx = hs[i] + inter, tx2 = ts[i] + inter;

  red[i] = hx * hx; __syncthreads();
  for (int s = 64; s > 0; s >>= 1) { if (i < s) red[i] += red[i + s]; __syncthreads(); }
  float hnorm = fmaxf(sqrtf(red[0]), 1e-12f);
  __syncthreads();
  red[i] = tx2 * tx2; __syncthreads();
  for (int s = 64; s > 0; s >>= 1) { if (i < s) red[i] += red[i + s]; __syncthreads(); }
  float tnorm = fmaxf(sqrtf(red[0]), 1e-12f);
  __syncthreads();
  hnv[i] = hx / hnorm; tnv[i] = tx2 / tnorm;
  __syncthreads();

  const float* R = rel_emb + (size_t)rels[b] * 16384 + (size_t)i * 128;
  float dot = 0.f, nrm = 0.f;
  for (int j = 0; j < 128; j++) { float r = R[j]; dot += r * tnv[j]; nrm += r * r; }
  float contrib = hnv[i] * dot / fmaxf(sqrtf(nrm), 1e-12f);
  red[i] = contrib; __syncthreads();
  for (int s = 64; s > 0; s >>= 1) { if (i < s) red[i] += red[i + s]; __syncthreads(); }
  if (i == 0) out[b] = red[0];
}

extern "C" void kernel_launch(void* const* d_in, const int* in_sizes, int n_in,
                              void* d_out, int out_size, void* d_ws, size_t ws_size,
                              hipStream_t stream)
{
  const float* h_x     = (const float*)d_in[0];
  const int*   h_ei    = (const int*)d_in[1];
  const int*   h_batch = (const int*)d_in[2];
  const float* t_x     = (const float*)d_in[3];
  const int*   t_ei    = (const int*)d_in[4];
  const int*   t_batch = (const int*)d_in[5];
  const int*   rels    = (const int*)d_in[6];
  const float* lin0_W  = (const float*)d_in[7];
  const float* lin0_b  = (const float*)d_in[8];
  const float* Wq      = (const float*)d_in[9];
  const float* bq      = (const float*)d_in[10];
  const float* Wk      = (const float*)d_in[11];
  const float* bk      = (const float*)d_in[12];
  const float* Wv      = (const float*)d_in[13];
  const float* bv      = (const float*)d_in[14];
  const float* Ws      = (const float*)d_in[15];
  const float* bs      = (const float*)d_in[16];
  const float* wqW     = (const float*)d_in[17];
  const float* wqb     = (const float*)d_in[18];
  const float* wkW     = (const float*)d_in[19];
  const float* wkb     = (const float*)d_in[20];
  const float* rel_emb = (const float*)d_in[21];

  const int N = in_sizes[2];          // 50000
  const int E = in_sizes[1] / 2;      // 400000
  const int G = in_sizes[6];          // 512
  const int inF = in_sizes[7] / 128;  // 70
  const int N2 = 2 * N;
  const int nPanels = (N + 127) / 128;     // per graph
  const int Npad = nPanels * 128;

  char* ws = (char*)d_ws;
  size_t off = 0;
  auto alloc = [&](size_t bytes) -> void* {
    void* p = ws + off; off += (bytes + 255) & ~(size_t)255; return p;
  };
  unsigned short* hbuf  = (unsigned short*)alloc((size_t)2 * nPanels * 16384 * 2);
  unsigned short* skipb = (unsigned short*)alloc((size_t)N * 128 * 2);
  unsigned short* qb    = (unsigned short*)alloc((size_t)N * 512 * 2);
  unsigned short* kvb   = (unsigned short*)alloc((size_t)N * 1024 * 2);
  unsigned short* BT    = (unsigned short*)alloc((size_t)3 * 212992 * 2);
  float* biascat        = (float*)alloc((size_t)3 * 1664 * 4);
  int* deg              = (int*)alloc((size_t)(N2 + 1) * 4);
  int* row_start        = (int*)alloc((size_t)(N2 + 1) * 4);
  int* cursor           = (int*)alloc((size_t)(N2 + 1) * 4);
  int* bsums            = (int*)alloc((size_t)1024 * 4);
  int* bsums_scan       = (int*)alloc((size_t)1024 * 4);
  int* csr_src          = (int*)alloc((size_t)2 * E * 4);
  float* emb            = (float*)alloc((size_t)2 * G * 128 * 4);
  (void)ws_size; (void)n_in; (void)out_size;

  const int nScanBlocks = (N2 + 255) / 256;

  wcvt_kernel<<<3 * 1664, 128, 0, stream>>>(Wq, bq, Wk, bk, Wv, bv, Ws, bs, BT, biascat);

  // --- combined CSR, one serial chain (t-graph dst ids offset by N) ---
  hipMemsetAsync(deg, 0, (size_t)(N2 + 1) * 4, stream);
  hist_kernel<<<(E + 255) / 256, 256, 0, stream>>>(h_ei + E, deg, E, 0);
  hist_kernel<<<(E + 255) / 256, 256, 0, stream>>>(t_ei + E, deg, E, N);
  scan_block_kernel<<<nScanBlocks, 256, 0, stream>>>(deg, row_start, bsums, N2);
  scan_seq_kernel<<<1, 256, 0, stream>>>(bsums, bsums_scan, nScanBlocks);
  scan_finish_kernel<<<nScanBlocks, 256, 0, stream>>>(row_start, cursor, bsums_scan, N2, 2 * E);
  scatter_kernel<<<(E + 255) / 256, 256, 0, stream>>>(h_ei, h_ei + E, cursor, csr_src, E, 0);
  scatter_kernel<<<(E + 255) / 256, 256, 0, stream>>>(t_ei, t_ei + E, cursor, csr_src, E, N);

  // --- lin0 for both graphs (8 nodes/block) ---
  lin0_kernel<<<(N2 + 7) / 8, 128, 0, stream>>>(h_x, t_x, lin0_W, lin0_b, hbuf, N, inF, Npad);

  hipMemsetAsync(emb, 0, (size_t)2 * G * 128 * 4, stream);

  for (int g = 0; g < 2; g++) {
    unsigned short* hb_g = hbuf + (size_t)g * nPanels * 16384;
    const int* rs_g = row_start + (size_t)g * N;
    for (int l = 0; l < 3; l++) {
      dim3 pg(nPanels, 13);
      proj_mfma_kernel<<<pg, 256, 0, stream>>>(hb_g,
          BT + (size_t)l * 212992, biascat + (size_t)l * 1664, N,
          qb, kvb, skipb);
      node_attn_kernel<<<(N + 3) / 4, 256, 0, stream>>>(qb, kvb, skipb,
          rs_g, csr_src, hb_g, N);
    }
    pool_kernel<<<(N + 127) / 128, 128, 0, stream>>>(hb_g,
        g ? t_batch : h_batch, emb + (size_t)g * G * 128, N);
  }

  score_kernel<<<G, 128, 0, stream>>>(emb, emb + (size_t)G * 128, rels,
                                      wqW, wqb, wkW, wkb, rel_emb, (float*)d_out);
}

// Round 9
// 1756.526 us; speedup vs baseline: 1.0661x; 1.0090x over previous
//
#include <hip/hip_runtime.h>
#include <math.h>

#define HID 128

typedef __attribute__((ext_vector_type(8))) short short8;
typedef __attribute__((ext_vector_type(4))) float f32x4;

__device__ __forceinline__ float bf2f(unsigned int u16) {
  union { unsigned int i; float f; } x; x.i = u16 << 16; return x.f;
}
__device__ __forceinline__ unsigned short f2bf(float f) {
  union { float f; unsigned int i; } x; x.f = f;
  unsigned int i = x.i;
  unsigned int r = i + 0x7FFFu + ((i >> 16) & 1u);
  return (unsigned short)(r >> 16);
}

// k-major panel layout: panel p = row>>7, chunk J = k>>3,
// elem addr = p*16384 + (J*128 + (row&127))*8 + (k&7).

// ---------------- weight convert: k-major panels + biascat ----------------
__global__ __launch_bounds__(128) void wcvt_kernel(
    const float* __restrict__ Wq, const float* __restrict__ bq,
    const float* __restrict__ Wk, const float* __restrict__ bk,
    const float* __restrict__ Wv, const float* __restrict__ bv,
    const float* __restrict__ Ws, const float* __restrict__ bs,
    unsigned short* __restrict__ BT, float* __restrict__ biascat)
{
  int id = blockIdx.x;
  int l = id / 1664;
  int n = id - l * 1664;
  int k = threadIdx.x;
  const float* W; const float* bias; int nl, ldb;
  if (n < 512)       { W = Wq + (size_t)l * 65536; bias = bq + (size_t)l * 512; nl = n;        ldb = 512; }
  else if (n < 1024) { W = Wk + (size_t)l * 65536; bias = bk + (size_t)l * 512; nl = n - 512;  ldb = 512; }
  else if (n < 1536) { W = Wv + (size_t)l * 65536; bias = bv + (size_t)l * 512; nl = n - 1024; ldb = 512; }
  else               { W = Ws + (size_t)l * 16384; bias = bs + (size_t)l * 128; nl = n - 1536; ldb = 128; }
  size_t dst = (size_t)l * 212992 + (size_t)(n >> 7) * 16384
             + (size_t)((k >> 3) * 128 + (n & 127)) * 8 + (k & 7);
  BT[dst] = f2bf(W[(size_t)k * ldb + nl]);
  if (k == 0) biascat[(size_t)l * 1664 + n] = bias[nl];
}

// ---------------- lin0 (both graphs, 8 nodes/block) ----------
__global__ __launch_bounds__(128) void lin0_kernel(
    const float* __restrict__ xh, const float* __restrict__ xt,
    const float* __restrict__ W, const float* __restrict__ b,
    unsigned short* __restrict__ hb, int N, int inF, int Npad)
{
  __shared__ float xs[8][72];
  const int t = threadIdx.x;
  const int nb = blockIdx.x * 8;
  if (t < inF) {
#pragma unroll
    for (int nn = 0; nn < 8; nn++) {
      int n = nb + nn;
      if (n < 2 * N) {
        const float* xp = (n < N) ? (xh + (size_t)n * inF) : (xt + (size_t)(n - N) * inF);
        xs[nn][t] = xp[t];
      }
    }
  }
  __syncthreads();
  float acc[8];
#pragma unroll
  for (int nn = 0; nn < 8; nn++) acc[nn] = b[t];
  for (int k = 0; k < inF; k++) {
    float w = W[(size_t)k * 128 + t];
#pragma unroll
    for (int nn = 0; nn < 8; nn++) acc[nn] += xs[nn][k] * w;
  }
#pragma unroll
  for (int nn = 0; nn < 8; nn++) {
    int n = nb + nn;
    if (n < 2 * N) {
      int g = (n >= N) ? 1 : 0;
      int row = g * Npad + (n - g * N);
      hb[(size_t)(row >> 7) * 16384 + (size_t)((t >> 3) * 128 + (row & 127)) * 8 + (t & 7)] = f2bf(acc[nn]);
    }
  }
}

// ---------------- MFMA projection GEMM (A-panel resident, 2 chunks/block) ----
// grid (nPanels, 7); LDS: full A panel 32 KB + B double-buffer 16 KB = 48 KB.
// Pair y covers column chunks 2y, 2y+1 (pair 6 covers only chunk 12).
__global__ __launch_bounds__(256) void proj_mfma_kernel(
    const unsigned short* __restrict__ A, const unsigned short* __restrict__ BT,
    const float* __restrict__ bias, int M,
    unsigned short* __restrict__ qo, unsigned short* __restrict__ kv,
    unsigned short* __restrict__ skipb)
{
  __shared__ unsigned short lsA[16384];
  __shared__ unsigned short lsB[2][4096];
  const int t = threadIdx.x;
  const int wv = t >> 6, ln = t & 63;
  const int wx = wv & 1, wy = wv >> 1;
  const int m0 = blockIdx.x * 128;
  const int pair = blockIdx.y;
  const int fr = ln & 15, quad = ln >> 4;

  const unsigned short* Ap = A + (size_t)blockIdx.x * 16384;

  // ---- stage full A panel (linear 32 KB copy) ----
#pragma unroll
  for (int it = 0; it < 8; it++) {
    const int c = it * 256 + t;
    __builtin_amdgcn_global_load_lds(
        (const __attribute__((address_space(1))) void*)(Ap + (size_t)c * 8),
        (__attribute__((address_space(3))) void*)((char*)lsA + c * 16), 16, 0, 0);
  }

  for (int c2 = 0; c2 < 2; c2++) {
    const int nc = pair * 2 + c2;
    if (nc >= 13) break;
    const unsigned short* Bp = BT + (size_t)nc * 16384;

    auto stageB = [&](int kb, int buf) {
#pragma unroll
      for (int it = 0; it < 2; it++) {
        const int c = it * 256 + t;
        __builtin_amdgcn_global_load_lds(
            (const __attribute__((address_space(1))) void*)(Bp + (size_t)kb * 4096 + c * 8),
            (__attribute__((address_space(3))) void*)((char*)lsB[buf] + c * 16), 16, 0, 0);
      }
    };

    f32x4 acc[4][4];
#pragma unroll
    for (int i = 0; i < 4; i++)
#pragma unroll
      for (int j = 0; j < 4; j++) acc[i][j] = (f32x4){0.f, 0.f, 0.f, 0.f};

    stageB(0, 0);
    for (int kb = 0; kb < 4; kb++) {
      __syncthreads();                        // staged data visible; prev reads done
      if (kb < 3) stageB(kb + 1, (kb + 1) & 1);
      const unsigned short* lb = lsB[kb & 1];
      short8 af[4], bf[4];
#pragma unroll
      for (int i = 0; i < 4; i++)
        af[i] = *(const short8*)(&lsA[(size_t)((kb * 4 + quad) * 128 + wy * 64 + i * 16 + fr) * 8]);
#pragma unroll
      for (int j = 0; j < 4; j++)
        bf[j] = *(const short8*)(&lb[(size_t)(quad * 128 + wx * 64 + j * 16 + fr) * 8]);
#pragma unroll
      for (int i = 0; i < 4; i++)
#pragma unroll
        for (int j = 0; j < 4; j++)
          acc[i][j] = __builtin_amdgcn_mfma_f32_16x16x32_bf16(bf[j], af[i], acc[i][j], 0, 0, 0);
    }

    const int region = nc >> 2;               // 0=q 1=k 2=v 3=skip
#pragma unroll
    for (int j = 0; j < 4; j++) {
      const int colb = nc * 128 + wx * 64 + j * 16 + quad * 4;
      const float4 b4 = *(const float4*)(&bias[colb]);
      const int col = colb - region * 512;
#pragma unroll
      for (int i = 0; i < 4; i++) {
        const int row = m0 + wy * 64 + i * 16 + fr;
        if (row < M) {
          f32x4 c = acc[i][j];
          uint2 pk;
          pk.x = (unsigned int)f2bf(c[0] + b4.x) | ((unsigned int)f2bf(c[1] + b4.y) << 16);
          pk.y = (unsigned int)f2bf(c[2] + b4.z) | ((unsigned int)f2bf(c[3] + b4.w) << 16);
          if (region == 0)      *(uint2*)(qo    + (size_t)row * 512  + col)       = pk;
          else if (region == 1) *(uint2*)(kv    + (size_t)row * 1024 + col)       = pk;
          else if (region == 2) *(uint2*)(kv    + (size_t)row * 1024 + 512 + col) = pk;
          else                  *(uint2*)(skipb + (size_t)row * 128  + col)       = pk;
        }
      }
    }
    __syncthreads();   // all lsB reads done before next chunk restages buf0
  }
}

// ---------------- combined CSR build (both graphs in one launch) -----------
__global__ __launch_bounds__(256) void hist_kernel(
    const int* __restrict__ hd, const int* __restrict__ td,
    int* __restrict__ deg, int E, int N)
{
  int e = blockIdx.x * 256 + threadIdx.x;
  if (e < E) atomicAdd(&deg[hd[e]], 1);
  else if (e < 2 * E) atomicAdd(&deg[td[e - E] + N], 1);
}

__global__ __launch_bounds__(256) void scan_block_kernel(
    const int* __restrict__ in, int* __restrict__ out, int* __restrict__ bsums, int N)
{
  __shared__ int sm[256];
  int i = blockIdx.x * 256 + threadIdx.x;
  int v = (i < N) ? in[i] : 0;
  sm[threadIdx.x] = v; __syncthreads();
  for (int off = 1; off < 256; off <<= 1) {
    int t = (threadIdx.x >= off) ? sm[threadIdx.x - off] : 0;
    __syncthreads();
    sm[threadIdx.x] += t;
    __syncthreads();
  }
  if (i < N) out[i] = sm[threadIdx.x] - v;   // exclusive
  if (threadIdx.x == 255 && bsums) bsums[blockIdx.x] = sm[255];
}

__global__ __launch_bounds__(256) void scan_seq_kernel(
    const int* __restrict__ in, int* __restrict__ out, int nb)
{
  __shared__ int sm[256];
  __shared__ int carry;
  if (threadIdx.x == 0) carry = 0;
  __syncthreads();
  for (int base = 0; base < nb; base += 256) {
    int i = base + threadIdx.x;
    int v = (i < nb) ? in[i] : 0;
    sm[threadIdx.x] = v; __syncthreads();
    for (int off = 1; off < 256; off <<= 1) {
      int t = (threadIdx.x >= off) ? sm[threadIdx.x - off] : 0;
      __syncthreads();
      sm[threadIdx.x] += t;
      __syncthreads();
    }
    if (i < nb) out[i] = carry + sm[threadIdx.x] - v;
    __syncthreads();
    if (threadIdx.x == 0) carry += sm[255];
    __syncthreads();
  }
}

__global__ __launch_bounds__(256) void scan_finish_kernel(
    int* __restrict__ row_start, int* __restrict__ cursor,
    const int* __restrict__ bsums_scan, int Ntot, int Etot)
{
  int i = blockIdx.x * 256 + threadIdx.x;
  if (i < Ntot) {
    int val = row_start[i] + bsums_scan[blockIdx.x];
    row_start[i] = val;
    cursor[i] = val;
  }
  if (i == 0) row_start[Ntot] = Etot;
}

// stores LOCAL src ids; dst offset selects the graph's region of row_start
__global__ __launch_bounds__(256) void scatter_kernel(
    const int* __restrict__ hs, const int* __restrict__ hd,
    const int* __restrict__ ts, const int* __restrict__ td,
    int* __restrict__ cursor, int* __restrict__ csr_src, int E, int N)
{
  int e = blockIdx.x * 256 + threadIdx.x;
  if (e < E) {
    int pos = atomicAdd(&cursor[hd[e]], 1);
    csr_src[pos] = hs[e];
  } else if (e < 2 * E) {
    int pos = atomicAdd(&cursor[td[e - E] + N], 1);
    csr_src[pos] = ts[e - E];
  }
}

// ---------------- fused per-node attention (one wave per dst node) ----------
__global__ __launch_bounds__(256) void node_attn_kernel(
    const unsigned short* __restrict__ q, const unsigned short* __restrict__ kv,
    const unsigned short* __restrict__ skipb,
    const int* __restrict__ row_start, const int* __restrict__ csr_src,
    unsigned short* __restrict__ hb, int N)
{
  int d = (blockIdx.x * 256 + threadIdx.x) >> 6;
  int lane = threadIdx.x & 63;
  if (d >= N) return;
  int beg = row_start[d], end = row_start[d + 1];

  const uint4 qv = *(const uint4*)(q + (size_t)d * 512 + lane * 8);
  float q0 = bf2f(qv.x & 0xFFFFu), q1 = bf2f(qv.x >> 16);
  float q2 = bf2f(qv.y & 0xFFFFu), q3 = bf2f(qv.y >> 16);
  float q4 = bf2f(qv.z & 0xFFFFu), q5 = bf2f(qv.z >> 16);
  float q6 = bf2f(qv.w & 0xFFFFu), q7 = bf2f(qv.w >> 16);

  float num[8] = {0.f,0.f,0.f,0.f,0.f,0.f,0.f,0.f};
  float den = 0.f;

  auto krow = [&](int s) { return *(const uint4*)(kv + (size_t)s * 1024 + lane * 8); };
  auto vrow = [&](int s) { return *(const uint4*)(kv + (size_t)s * 1024 + 512 + lane * 8); };
  auto accum = [&](const uint4& kk, const uint4& vv) {
    float p = q0 * bf2f(kk.x & 0xFFFFu) + q1 * bf2f(kk.x >> 16)
            + q2 * bf2f(kk.y & 0xFFFFu) + q3 * bf2f(kk.y >> 16)
            + q4 * bf2f(kk.z & 0xFFFFu) + q5 * bf2f(kk.z >> 16)
            + q6 * bf2f(kk.w & 0xFFFFu) + q7 * bf2f(kk.w >> 16);
    p += __shfl_xor(p, 1);
    p += __shfl_xor(p, 2);
    p += __shfl_xor(p, 4);
    p += __shfl_xor(p, 8);
    float e = __expf(p * 0.08838834764831845f);  // 1/sqrt(128)
    den += e;
    num[0] += e * bf2f(vv.x & 0xFFFFu); num[1] += e * bf2f(vv.x >> 16);
    num[2] += e * bf2f(vv.y & 0xFFFFu); num[3] += e * bf2f(vv.y >> 16);
    num[4] += e * bf2f(vv.z & 0xFFFFu); num[5] += e * bf2f(vv.z >> 16);
    num[6] += e * bf2f(vv.w & 0xFFFFu); num[7] += e * bf2f(vv.w >> 16);
  };

  if (beg < end) {
    const int last = end - 1;
    int sA = csr_src[beg];
    int sB = csr_src[min(beg + 1, last)];
    uint4 kA = krow(sA), vA = vrow(sA);
    uint4 kB = krow(sB), vB = vrow(sB);
    for (int i = beg; i < end; i += 2) {
      int sC = csr_src[min(i + 2, last)];
      int sD = csr_src[min(i + 3, last)];
      uint4 kC = krow(sC), vC = vrow(sC);
      uint4 kD = krow(sD), vD = vrow(sD);
      accum(kA, vA);
      if (i + 1 < end) accum(kB, vB);
      kA = kC; vA = vC; kB = kD; vB = vD;
    }
  }

  float inv = (den > 0.f) ? 0.25f / den : 0.f;
#pragma unroll
  for (int j = 0; j < 8; j++) {
    float r = num[j] * inv;
    r += __shfl_xor(r, 16);   // combine 4 heads
    r += __shfl_xor(r, 32);
    num[j] = r;
  }
  if (lane < 16) {
    const uint4 sv = *(const uint4*)(skipb + (size_t)d * 128 + lane * 8);
    float o0 = fmaxf(bf2f(sv.x & 0xFFFFu) + num[0], 0.f);
    float o1 = fmaxf(bf2f(sv.x >> 16)     + num[1], 0.f);
    float o2 = fmaxf(bf2f(sv.y & 0xFFFFu) + num[2], 0.f);
    float o3 = fmaxf(bf2f(sv.y >> 16)     + num[3], 0.f);
    float o4 = fmaxf(bf2f(sv.z & 0xFFFFu) + num[4], 0.f);
    float o5 = fmaxf(bf2f(sv.z >> 16)     + num[5], 0.f);
    float o6 = fmaxf(bf2f(sv.w & 0xFFFFu) + num[6], 0.f);
    float o7 = fmaxf(bf2f(sv.w >> 16)     + num[7], 0.f);
    uint4 hv;
    hv.x = (unsigned int)f2bf(o0) | ((unsigned int)f2bf(o1) << 16);
    hv.y = (unsigned int)f2bf(o2) | ((unsigned int)f2bf(o3) << 16);
    hv.z = (unsigned int)f2bf(o4) | ((unsigned int)f2bf(o5) << 16);
    hv.w = (unsigned int)f2bf(o6) | ((unsigned int)f2bf(o7) << 16);
    *(uint4*)(hb + (size_t)(d >> 7) * 16384 + (size_t)(lane * 128 + (d & 127)) * 8) = hv;
  }
}

// ---------------- pooling from bf16 panels, both graphs ----------------
__global__ __launch_bounds__(128) void pool_kernel(
    const unsigned short* __restrict__ hb, const int* __restrict__ bh,
    const int* __restrict__ bt, float* __restrict__ emb, int N, int G, int Npad)
{
  int dth = threadIdx.x;
  int n0 = blockIdx.x * 128;
  int n1 = min(n0 + 128, 2 * N);
  float acc = 0.f; int cur = -1;
  for (int n = n0; n < n1; n++) {
    int g = (n < N) ? 0 : 1;
    int local = n - g * N;
    int gid = g ? (G + bt[local]) : bh[local];
    if (gid != cur) {
      if (cur >= 0) atomicAdd(&emb[(size_t)cur * 128 + dth], acc);
      cur = gid; acc = 0.f;
    }
    int row = g * Npad + local;
    acc += bf2f(hb[(size_t)(row >> 7) * 16384
                   + (size_t)((dth >> 3) * 128 + (row & 127)) * 8 + (dth & 7)]);
  }
  if (cur >= 0) atomicAdd(&emb[(size_t)cur * 128 + dth], acc);
}

// ---------------- final score ----------------
__global__ __launch_bounds__(128) void score_kernel(
    const float* __restrict__ hemb, const float* __restrict__ temb,
    const int* __restrict__ rels,
    const float* __restrict__ wqW, const float* __restrict__ wqb,
    const float* __restrict__ wkW, const float* __restrict__ wkb,
    const float* __restrict__ rel_emb, float* __restrict__ out)
{
  const int b = blockIdx.x, i = threadIdx.x;
  __shared__ float hs[128], ts[128], hnv[128], tnv[128], red[128];
  hs[i] = hemb[(size_t)b * 128 + i];
  ts[i] = temb[(size_t)b * 128 + i];
  __syncthreads();
  float qv = wqb[i], kv = wkb[i];
  for (int k = 0; k < 128; k++) {
    qv += hs[k] * wqW[k * 128 + i];
    kv += ts[k] * wkW[k * 128 + i];
  }
  float inter = tanhf(qv * kv);
  float hx = hs[i] + inter, tx2 = ts[i] + inter;

  red[i] = hx * hx; __syncthreads();
  for (int s = 64; s > 0; s >>= 1) { if (i < s) red[i] += red[i + s]; __syncthreads(); }
  float hnorm = fmaxf(sqrtf(red[0]), 1e-12f);
  __syncthreads();
  red[i] = tx2 * tx2; __syncthreads();
  for (int s = 64; s > 0; s >>= 1) { if (i < s) red[i] += red[i + s]; __syncthreads(); }
  float tnorm = fmaxf(sqrtf(red[0]), 1e-12f);
  __syncthreads();
  hnv[i] = hx / hnorm; tnv[i] = tx2 / tnorm;
  __syncthreads();

  const float* R = rel_emb + (size_t)rels[b] * 16384 + (size_t)i * 128;
  float dot = 0.f, nrm = 0.f;
  for (int j = 0; j < 128; j++) { float r = R[j]; dot += r * tnv[j]; nrm += r * r; }
  float contrib = hnv[i] * dot / fmaxf(sqrtf(nrm), 1e-12f);
  red[i] = contrib; __syncthreads();
  for (int s = 64; s > 0; s >>= 1) { if (i < s) red[i] += red[i + s]; __syncthreads(); }
  if (i == 0) out[b] = red[0];
}

extern "C" void kernel_launch(void* const* d_in, const int* in_sizes, int n_in,
                              void* d_out, int out_size, void* d_ws, size_t ws_size,
                              hipStream_t stream)
{
  const float* h_x     = (const float*)d_in[0];
  const int*   h_ei    = (const int*)d_in[1];
  const int*   h_batch = (const int*)d_in[2];
  const float* t_x     = (const float*)d_in[3];
  const int*   t_ei    = (const int*)d_in[4];
  const int*   t_batch = (const int*)d_in[5];
  const int*   rels    = (const int*)d_in[6];
  const float* lin0_W  = (const float*)d_in[7];
  const float* lin0_b  = (const float*)d_in[8];
  const float* Wq      = (const float*)d_in[9];
  const float* bq      = (const float*)d_in[10];
  const float* Wk      = (const float*)d_in[11];
  const float* bk      = (const float*)d_in[12];
  const float* Wv      = (const float*)d_in[13];
  const float* bv      = (const float*)d_in[14];
  const float* Ws      = (const float*)d_in[15];
  const float* bs      = (const float*)d_in[16];
  const float* wqW     = (const float*)d_in[17];
  const float* wqb     = (const float*)d_in[18];
  const float* wkW     = (const float*)d_in[19];
  const float* wkb     = (const float*)d_in[20];
  const float* rel_emb = (const float*)d_in[21];

  const int N = in_sizes[2];          // 50000
  const int E = in_sizes[1] / 2;      // 400000
  const int G = in_sizes[6];          // 512
  const int inF = in_sizes[7] / 128;  // 70
  const int N2 = 2 * N;
  const int nPanels = (N + 127) / 128;     // per graph
  const int Npad = nPanels * 128;

  char* ws = (char*)d_ws;
  size_t off = 0;
  auto alloc = [&](size_t bytes) -> void* {
    void* p = ws + off; off += (bytes + 255) & ~(size_t)255; return p;
  };
  unsigned short* hbuf  = (unsigned short*)alloc((size_t)2 * nPanels * 16384 * 2);
  unsigned short* skipb = (unsigned short*)alloc((size_t)N * 128 * 2);
  unsigned short* qb    = (unsigned short*)alloc((size_t)N * 512 * 2);
  unsigned short* kvb   = (unsigned short*)alloc((size_t)N * 1024 * 2);
  unsigned short* BT    = (unsigned short*)alloc((size_t)3 * 212992 * 2);
  float* biascat        = (float*)alloc((size_t)3 * 1664 * 4);
  int* deg              = (int*)alloc((size_t)(N2 + 1) * 4);
  int* row_start        = (int*)alloc((size_t)(N2 + 1) * 4);
  int* cursor           = (int*)alloc((size_t)(N2 + 1) * 4);
  int* bsums            = (int*)alloc((size_t)1024 * 4);
  int* bsums_scan       = (int*)alloc((size_t)1024 * 4);
  int* csr_src          = (int*)alloc((size_t)2 * E * 4);
  float* emb            = (float*)alloc((size_t)2 * G * 128 * 4);
  (void)ws_size; (void)n_in; (void)out_size;

  const int nScanBlocks = (N2 + 255) / 256;

  wcvt_kernel<<<3 * 1664, 128, 0, stream>>>(Wq, bq, Wk, bk, Wv, bv, Ws, bs, BT, biascat);

  // --- combined CSR, one serial chain (t-graph dst ids offset by N) ---
  hipMemsetAsync(deg, 0, (size_t)(N2 + 1) * 4, stream);
  hist_kernel<<<(2 * E + 255) / 256, 256, 0, stream>>>(h_ei + E, t_ei + E, deg, E, N);
  scan_block_kernel<<<nScanBlocks, 256, 0, stream>>>(deg, row_start, bsums, N2);
  scan_seq_kernel<<<1, 256, 0, stream>>>(bsums, bsums_scan, nScanBlocks);
  scan_finish_kernel<<<nScanBlocks, 256, 0, stream>>>(row_start, cursor, bsums_scan, N2, 2 * E);
  scatter_kernel<<<(2 * E + 255) / 256, 256, 0, stream>>>(h_ei, h_ei + E, t_ei, t_ei + E,
                                                          cursor, csr_src, E, N);

  // --- lin0 for both graphs (8 nodes/block) ---
  lin0_kernel<<<(N2 + 7) / 8, 128, 0, stream>>>(h_x, t_x, lin0_W, lin0_b, hbuf, N, inF, Npad);

  hipMemsetAsync(emb, 0, (size_t)2 * G * 128 * 4, stream);

  for (int g = 0; g < 2; g++) {
    unsigned short* hb_g = hbuf + (size_t)g * nPanels * 16384;
    const int* rs_g = row_start + (size_t)g * N;
    for (int l = 0; l < 3; l++) {
      dim3 pg(nPanels, 7);
      proj_mfma_kernel<<<pg, 256, 0, stream>>>(hb_g,
          BT + (size_t)l * 212992, biascat + (size_t)l * 1664, N,
          qb, kvb, skipb);
      node_attn_kernel<<<(N + 3) / 4, 256, 0, stream>>>(qb, kvb, skipb,
          rs_g, csr_src, hb_g, N);
    }
  }
  pool_kernel<<<(N2 + 127) / 128, 128, 0, stream>>>(hbuf, h_batch, t_batch,
                                                    emb, N, G, Npad);

  score_kernel<<<G, 128, 0, stream>>>(emb, emb + (size_t)G * 128, rels,
                                      wqW, wqb, wkW, wkb, rel_emb, (float*)d_out);
}